// Round 9
// baseline (314.223 us; speedup 1.0000x reference)
//
#include <hip/hip_runtime.h>
#include <cstdint>
#include <cmath>

// Causal self-attention: x[B,T,C] -> QKV proj -> flash attn -> out proj.
// B=4 T=2048 C=1024 H=16 DH=64. All matmuls in bf16 MFMA, fp32 accumulate.

#define Bb 4
#define Tt 2048
#define Cc 1024
#define Hh 16
#define DHd 64
#define Mm (Bb*Tt)   // 8192

typedef __attribute__((ext_vector_type(8))) short bf16x8;
typedef __attribute__((ext_vector_type(4))) short s16x4;
typedef __attribute__((ext_vector_type(4))) float f32x4;
typedef __attribute__((ext_vector_type(2))) unsigned int u32x2;

__device__ __forceinline__ short f2bf(float f) {
  uint32_t u = __builtin_bit_cast(uint32_t, f);
  u = (u + 0x7fffu + ((u >> 16) & 1u)) >> 16;   // RNE
  return (short)(uint16_t)u;
}

__device__ __forceinline__ uint32_t cvtpk(float lo, float hi) {
  uint32_t r;
  asm("v_cvt_pk_bf16_f32 %0, %1, %2" : "=v"(r) : "v"(lo), "v"(hi));
  return r;
}

// K=16 bf16 MFMA (P stays in registers as the B operand)
__device__ __forceinline__ f32x4 mfma16(s16x4 a, s16x4 b, f32x4 c) {
#if __has_builtin(__builtin_amdgcn_mfma_f32_16x16x16_bf16)
  return __builtin_amdgcn_mfma_f32_16x16x16_bf16(a, b, c, 0, 0, 0);
#elif __has_builtin(__builtin_amdgcn_mfma_f32_16x16x16bf16_1k)
  return __builtin_amdgcn_mfma_f32_16x16x16bf16_1k(a, b, c, 0, 0, 0);
#else
  f32x4 d;
  asm("v_mfma_f32_16x16x16_bf16 %0, %1, %2, %3" : "=v"(d) : "v"(a), "v"(b), "v"(c));
  return d;
#endif
}

// ---------------- fp32 -> bf16 convert (x4 vectorized) ----------------
__global__ void cvt_bf16(const float* __restrict__ in, short* __restrict__ out, int n4) {
  int i = blockIdx.x * blockDim.x + threadIdx.x;
  if (i >= n4) return;
  f32x4 v = reinterpret_cast<const f32x4*>(in)[i];
  s16x4 o;
  o.x = f2bf(v.x); o.y = f2bf(v.y); o.z = f2bf(v.z); o.w = f2bf(v.w);
  reinterpret_cast<s16x4*>(out)[i] = o;
}

// ---------------- 128x128 bf16 GEMM, C = A * Bt^T (both K-contiguous) ----------------
// MODE 0: QKV epilogue -> scatter to q [B,H,T,64] (scaled log2e/8), k [B,H,T,64],
//         and V TRANSPOSED vt [B,H,64,T] (packed b64 stores along t)
// MODE 1: plain fp32 store to Cout [M,N]
#define BK 32

template<int MODE>
__global__ __launch_bounds__(256) void gemm_bt(
    const short* __restrict__ A, const short* __restrict__ Bt, int K, int N,
    float* __restrict__ Cout,
    short* __restrict__ qb, short* __restrict__ kb, short* __restrict__ vtb)
{
  __shared__ __align__(16) short As[128*BK];
  __shared__ __align__(16) short Bs[128*BK];
  const int tid = threadIdx.x;
  const int lane = tid & 63, wid = tid >> 6;
  const int wr = wid >> 1, wc = wid & 1;
  const int bm = blockIdx.y, bn = blockIdx.x;
  const int r16 = lane & 15, g = lane >> 4;

  f32x4 acc[4][4];
#pragma unroll
  for (int i = 0; i < 4; ++i)
#pragma unroll
    for (int j = 0; j < 4; ++j) acc[i][j] = (f32x4)0.0f;

  const int srow = lane >> 2;
  const int scol = (lane & 3) * 8;
  const int ch0 = wid * 2;

  const int nk = K / BK;
  for (int kt = 0; kt < nk; ++kt) {
    const int k0 = kt * BK;
#pragma unroll
    for (int c = 0; c < 2; ++c) {
      const int chunk = ch0 + c;
      const int row = chunk * 16 + srow;
      const short* ga = A  + (size_t)(bm*128 + row)*K + k0 + scol;
      const short* gb = Bt + (size_t)(bn*128 + row)*K + k0 + scol;
      __builtin_amdgcn_global_load_lds((const __attribute__((address_space(1))) void*)ga,
                                       (__attribute__((address_space(3))) void*)(&As[chunk*512]), 16, 0, 0);
      __builtin_amdgcn_global_load_lds((const __attribute__((address_space(1))) void*)gb,
                                       (__attribute__((address_space(3))) void*)(&Bs[chunk*512]), 16, 0, 0);
    }
    __syncthreads();

    bf16x8 af[4], bfv[4];
#pragma unroll
    for (int mi = 0; mi < 4; ++mi)
      af[mi] = *reinterpret_cast<const bf16x8*>(&As[(wr*64 + mi*16 + r16)*BK + g*8]);
#pragma unroll
    for (int ni = 0; ni < 4; ++ni)
      bfv[ni] = *reinterpret_cast<const bf16x8*>(&Bs[(wc*64 + ni*16 + r16)*BK + g*8]);
#pragma unroll
    for (int mi = 0; mi < 4; ++mi)
#pragma unroll
      for (int ni = 0; ni < 4; ++ni)
        acc[mi][ni] = __builtin_amdgcn_mfma_f32_16x16x32_bf16(af[mi], bfv[ni], acc[mi][ni], 0, 0, 0);
    __syncthreads();
  }

  // epilogue: D layout col = lane&15, row = (lane>>4)*4 + r
#pragma unroll
  for (int mi = 0; mi < 4; ++mi) {
    const int row0 = bm*128 + wr*64 + mi*16 + g*4;
#pragma unroll
    for (int ni = 0; ni < 4; ++ni) {
      const int col_g = bn*128 + wc*64 + ni*16 + r16;
      if (MODE == 1) {
#pragma unroll
        for (int r = 0; r < 4; ++r)
          Cout[(size_t)(row0 + r) * N + col_g] = acc[mi][ni][r];
      } else {
        const int which = col_g >> 10;          // 0=q 1=k 2=v
        const int hd = col_g & 1023;
        const int h = hd >> 6, d = hd & 63;
        const int b = row0 >> 11, t0 = row0 & 2047;
        const int bh = b*Hh + h;
        if (which == 0) {
#pragma unroll
          for (int r = 0; r < 4; ++r)
            qb[(((size_t)bh*Tt + t0 + r) << 6) + d] = f2bf(acc[mi][ni][r] * 0.18033688f); // log2e/8
        } else if (which == 1) {
#pragma unroll
          for (int r = 0; r < 4; ++r)
            kb[(((size_t)bh*Tt + t0 + r) << 6) + d] = f2bf(acc[mi][ni][r]);
        } else {
          // transposed V: t contiguous along register index -> one packed b64 store
          u32x2 w;
          w.x = cvtpk(acc[mi][ni][0], acc[mi][ni][1]);
          w.y = cvtpk(acc[mi][ni][2], acc[mi][ni][3]);
          *reinterpret_cast<u32x2*>(vtb + ((size_t)bh*DHd + d)*Tt + t0) = w;
        }
      }
    }
  }
}

// ---------------- flash attention: ZERO-LDS, ZERO-BARRIER ----------------
// 4096 blocks of 64 threads (1 wave). Each wave owns 32 q rows, fully
// independent -> dynamic scheduling pool, no lockstep. All MFMA operands
// loaded DIRECTLY from global (L2-resident via XCD clustering: 8 heads'
// K/V = 4MB per XCD L2). K-frags prefetched one tile ahead; V-frags
// pipelined per-dt with static double-naming; am prefetched.
__global__ __launch_bounds__(64, 3) void attn_fwd(
    const short* __restrict__ qbf, const short* __restrict__ kbf,
    const short* __restrict__ vtb, const int* __restrict__ am,
    short* __restrict__ ob)
{
  const int lane = threadIdx.x;
  const int r16 = lane & 15, g = lane >> 4;

  const int lin = blockIdx.x;            // 0..4095
  const int xcd = lin & 7;
  const int idx = lin >> 3;              // 0..511
  const int bh  = xcd * 8 + (idx & 7);   // 8 heads per XCD cluster
  const int widx = idx >> 3;             // 0..63
  const int wq0 = (63 - widx) * 32;      // heavy-first
  const int b = bh >> 4, h = bh & 15;

  const short* kb_ = kbf + (size_t)bh * Tt * DHd;
  const short* vb_ = vtb + (size_t)bh * DHd * Tt;

  // Q fragments (B-operand of swapped QK^T): q-col = r16, k = g*8+e
  bf16x8 qf[2][2];
#pragma unroll
  for (int m = 0; m < 2; ++m) {
    const short* qbase = qbf + ((size_t)bh*Tt + wq0 + m*16 + r16)*DHd;
    qf[m][0] = *reinterpret_cast<const bf16x8*>(qbase + g*8);
    qf[m][1] = *reinterpret_cast<const bf16x8*>(qbase + 32 + g*8);
  }

  f32x4 o[2][4];
  float mrow[2], lrow[2];
#pragma unroll
  for (int m = 0; m < 2; ++m) {
    mrow[m] = -INFINITY; lrow[m] = 0.f;
#pragma unroll
    for (int i = 0; i < 4; ++i) o[m][i] = (f32x4)0.0f;
  }

  const int nkvw = (wq0 >> 6) + 1;       // tiles this wave needs
  int amv = am[b*Tt + lane];

  // K-frag prologue (tile 0): A-frag row = k (kt*16+r16), cols d = g*8(+32)
  bf16x8 kf0[4], kf1[4];
#pragma unroll
  for (int kt = 0; kt < 4; ++kt) {
    const short* kr = kb_ + (size_t)(kt*16 + r16)*DHd + g*8;
    kf0[kt] = *reinterpret_cast<const bf16x8*>(kr);
    kf1[kt] = *reinterpret_cast<const bf16x8*>(kr + 32);
  }

  for (int kv = 0; kv < nkvw; ++kv) {
    const int kv0 = kv * 64;
    const unsigned long long mb = __ballot(amv != 0);

    // ---- S^T = K · Q^T (16x16x32), K direct from registers ----
    f32x4 st[2][4];
    __builtin_amdgcn_s_setprio(1);
#pragma unroll
    for (int kt = 0; kt < 4; ++kt) {
#pragma unroll
      for (int m = 0; m < 2; ++m) {
        f32x4 t = (f32x4)0.0f;
        t = __builtin_amdgcn_mfma_f32_16x16x32_bf16(kf0[kt], qf[m][0], t, 0, 0, 0);
        t = __builtin_amdgcn_mfma_f32_16x16x32_bf16(kf1[kt], qf[m][1], t, 0, 0, 0);
        st[m][kt] = t;
      }
    }
    __builtin_amdgcn_s_setprio(0);

    // ---- prefetch K-frags + am for next tile (kf regs dead after QK issue) ----
    int amv_next = 0;
    if (kv + 1 < nkvw) {
      const short* kn = kb_ + (size_t)(kv0 + 64)*DHd;
#pragma unroll
      for (int kt = 0; kt < 4; ++kt) {
        const short* kr = kn + (size_t)(kt*16 + r16)*DHd + g*8;
        kf0[kt] = *reinterpret_cast<const bf16x8*>(kr);
        kf1[kt] = *reinterpret_cast<const bf16x8*>(kr + 32);
      }
      amv_next = am[b*Tt + kv0 + 64 + lane];
    }

    // ---- prefetch V-frags for dt=0 (A-frag row=d, k-elems = kt*16+g*4) ----
    s16x4 va[4], vb2[4];
#pragma unroll
    for (int kt = 0; kt < 4; ++kt)
      va[kt] = *reinterpret_cast<const s16x4*>(vb_ + (size_t)r16*Tt + kv0 + kt*16 + g*4);

    // ---- masking (wave-uniform outer branch) ----
    const bool notall = (mb != ~0ull);
    const bool diag = (kv0 + 63 > wq0);
    if (diag || notall) {
#pragma unroll
      for (int m = 0; m < 2; ++m) {
        const int qrow = wq0 + m*16 + r16;
#pragma unroll
        for (int kt = 0; kt < 4; ++kt)
#pragma unroll
          for (int r = 0; r < 4; ++r) {
            const int kl = kt*16 + g*4 + r;
            bool ok = !diag || (kv0 + kl <= qrow);
            if (notall) ok = ok && ((mb >> kl) & 1ull);
            if (!ok) st[m][kt][r] = -3.0e38f;
          }
      }
    }

    // ---- in-register online softmax + defer-rescale (THR=8, log2 domain) ----
    float mx[2], rs[2];
#pragma unroll
    for (int m = 0; m < 2; ++m) {
      f32x4 t0, t1;
#pragma unroll
      for (int i = 0; i < 4; ++i) { t0[i] = fmaxf(st[m][0][i], st[m][1][i]); t1[i] = fmaxf(st[m][2][i], st[m][3][i]); }
#pragma unroll
      for (int i = 0; i < 4; ++i) t0[i] = fmaxf(t0[i], t1[i]);
      mx[m] = fmaxf(fmaxf(t0[0], t0[1]), fmaxf(t0[2], t0[3]));
    }
    {
      float a0 = __shfl_xor(mx[0], 16), a1 = __shfl_xor(mx[1], 16);
      mx[0] = fmaxf(mx[0], a0); mx[1] = fmaxf(mx[1], a1);
      a0 = __shfl_xor(mx[0], 32); a1 = __shfl_xor(mx[1], 32);
      mx[0] = fmaxf(mx[0], a0); mx[1] = fmaxf(mx[1], a1);
    }
    const bool need = __any((mx[0] > mrow[0] + 8.f) || (mx[1] > mrow[1] + 8.f));
    if (need) {
#pragma unroll
      for (int m = 0; m < 2; ++m) {
        const float mnew = fmaxf(mrow[m], mx[m]);
        const float alpha = __builtin_amdgcn_exp2f(mrow[m] - mnew);
        mrow[m] = mnew;
        lrow[m] *= alpha;
#pragma unroll
        for (int dt = 0; dt < 4; ++dt) o[m][dt] *= alpha;
      }
    }

    // exp + pack P (B-frags of 16x16x16: k = g*4+e per kt)
    s16x4 pb[2][4];
    float rsum[2];
#pragma unroll
    for (int m = 0; m < 2; ++m) {
#pragma unroll
      for (int kt = 0; kt < 4; ++kt)
#pragma unroll
        for (int r = 0; r < 4; ++r)
          st[m][kt][r] = __builtin_amdgcn_exp2f(st[m][kt][r] - mrow[m]);
#pragma unroll
      for (int kt = 0; kt < 4; ++kt) {
        u32x2 w;
        w.x = cvtpk(st[m][kt][0], st[m][kt][1]);
        w.y = cvtpk(st[m][kt][2], st[m][kt][3]);
        pb[m][kt] = __builtin_bit_cast(s16x4, w);
      }
      f32x4 s4;
#pragma unroll
      for (int i = 0; i < 4; ++i) s4[i] = st[m][0][i] + st[m][1][i] + st[m][2][i] + st[m][3][i];
      rsum[m] = (s4[0] + s4[1]) + (s4[2] + s4[3]);
    }
    {
      float a0 = __shfl_xor(rsum[0], 16), a1 = __shfl_xor(rsum[1], 16);
      rsum[0] += a0; rsum[1] += a1;
      a0 = __shfl_xor(rsum[0], 32); a1 = __shfl_xor(rsum[1], 32);
      rsum[0] += a0; rsum[1] += a1;
    }
    lrow[0] += rsum[0]; lrow[1] += rsum[1];
    rs[0] = rs[1] = 0.f; (void)rs;

    // ---- O^T += Vt · P^T : 16x16x16 MFMA, V direct from global (pipelined) ----
    __builtin_amdgcn_s_setprio(1);
    // dt=0: compute with va, prefetch dt=1 into vb2
#pragma unroll
    for (int kt = 0; kt < 4; ++kt)
      vb2[kt] = *reinterpret_cast<const s16x4*>(vb_ + (size_t)(16 + r16)*Tt + kv0 + kt*16 + g*4);
#pragma unroll
    for (int kt = 0; kt < 4; ++kt) {
      o[0][0] = mfma16(va[kt], pb[0][kt], o[0][0]);
      o[1][0] = mfma16(va[kt], pb[1][kt], o[1][0]);
    }
    // dt=1: compute with vb2, prefetch dt=2 into va
#pragma unroll
    for (int kt = 0; kt < 4; ++kt)
      va[kt] = *reinterpret_cast<const s16x4*>(vb_ + (size_t)(32 + r16)*Tt + kv0 + kt*16 + g*4);
#pragma unroll
    for (int kt = 0; kt < 4; ++kt) {
      o[0][1] = mfma16(vb2[kt], pb[0][kt], o[0][1]);
      o[1][1] = mfma16(vb2[kt], pb[1][kt], o[1][1]);
    }
    // dt=2: compute with va, prefetch dt=3 into vb2
#pragma unroll
    for (int kt = 0; kt < 4; ++kt)
      vb2[kt] = *reinterpret_cast<const s16x4*>(vb_ + (size_t)(48 + r16)*Tt + kv0 + kt*16 + g*4);
#pragma unroll
    for (int kt = 0; kt < 4; ++kt) {
      o[0][2] = mfma16(va[kt], pb[0][kt], o[0][2]);
      o[1][2] = mfma16(va[kt], pb[1][kt], o[1][2]);
    }
    // dt=3: compute with vb2
#pragma unroll
    for (int kt = 0; kt < 4; ++kt) {
      o[0][3] = mfma16(vb2[kt], pb[0][kt], o[0][3]);
      o[1][3] = mfma16(vb2[kt], pb[1][kt], o[1][3]);
    }
    __builtin_amdgcn_s_setprio(0);

    amv = amv_next;
  }

  // ---- normalize + store O (lane holds q=r16, d=dt*16+g*4+r contiguous) ----
#pragma unroll
  for (int m = 0; m < 2; ++m) {
    const float inv = (mrow[m] > -1e37f) ? 1.0f / lrow[m] : 0.f;
    short* obase = ob + ((size_t)(b*Tt + wq0 + m*16 + r16))*Cc + h*DHd;
#pragma unroll
    for (int dt = 0; dt < 4; ++dt) {
      u32x2 w;
      w.x = cvtpk(o[m][dt][0]*inv, o[m][dt][1]*inv);
      w.y = cvtpk(o[m][dt][2]*inv, o[m][dt][3]*inv);
      *reinterpret_cast<u32x2*>(obase + dt*16 + g*4) = w;
    }
  }
}

// ---------------- launcher ----------------
extern "C" void kernel_launch(void* const* d_in, const int* in_sizes, int n_in,
                              void* d_out, int out_size, void* d_ws, size_t ws_size,
                              hipStream_t stream) {
  const float* x    = (const float*)d_in[0];
  const int*   am   = (const int*)d_in[1];
  const float* wqkv = (const float*)d_in[2];
  const float* wout = (const float*)d_in[3];
  float* out = (float*)d_out;

  const size_t mc = (size_t)Mm * Cc;        // 8,388,608
  short* ws    = (short*)d_ws;
  short* xb    = ws;                        // [8192,1024] bf16
  short* wqkvb = xb + mc;                   // [3072,1024]
  short* woutb = wqkvb + (size_t)3*Cc*Cc;   // [1024,1024]
  short* qbuf  = woutb + (size_t)Cc*Cc;     // [B,H,T,64] (pre-scaled by log2e/8)
  short* kbuf  = qbuf + mc;                 // [B,H,T,64]
  short* vtbuf = kbuf + mc;                 // [B,H,64,T] (transposed V)
  short* attnb = xb;                        // reuse x buffer after QKV GEMM

  cvt_bf16<<<(int)((mc/4 + 255)/256), 256, 0, stream>>>(x, xb, (int)(mc/4));
  cvt_bf16<<<(3*Cc*Cc/4 + 255)/256, 256, 0, stream>>>(wqkv, wqkvb, 3*Cc*Cc/4);
  cvt_bf16<<<(Cc*Cc/4 + 255)/256, 256, 0, stream>>>(wout, woutb, Cc*Cc/4);

  gemm_bt<0><<<dim3(3*Cc/128, Mm/128), 256, 0, stream>>>(
      xb, wqkvb, Cc, 3*Cc, nullptr, qbuf, kbuf, vtbuf);

  attn_fwd<<<dim3(4096), 64, 0, stream>>>(qbuf, kbuf, vtbuf, am, attnb);

  gemm_bt<1><<<dim3(Cc/128, Mm/128), 256, 0, stream>>>(
      attnb, woutb, Cc, Cc, out, nullptr, nullptr, nullptr);
}

// Round 10
// 219.423 us; speedup vs baseline: 1.4320x; 1.4320x over previous
//
#include <hip/hip_runtime.h>
#include <cstdint>
#include <cmath>

// Causal self-attention: x[B,T,C] -> QKV proj -> flash attn -> out proj.
// B=4 T=2048 C=1024 H=16 DH=64. All matmuls in bf16 MFMA, fp32 accumulate.

#define Bb 4
#define Tt 2048
#define Cc 1024
#define Hh 16
#define DHd 64
#define Mm (Bb*Tt)   // 8192

typedef __attribute__((ext_vector_type(8))) short bf16x8;
typedef __attribute__((ext_vector_type(4))) short s16x4;
typedef __attribute__((ext_vector_type(4))) float f32x4;
typedef __attribute__((ext_vector_type(2))) unsigned int u32x2;

__device__ __forceinline__ short f2bf(float f) {
  uint32_t u = __builtin_bit_cast(uint32_t, f);
  u = (u + 0x7fffu + ((u >> 16) & 1u)) >> 16;   // RNE
  return (short)(uint16_t)u;
}

__device__ __forceinline__ uint32_t cvtpk(float lo, float hi) {
  uint32_t r;
  asm("v_cvt_pk_bf16_f32 %0, %1, %2" : "=v"(r) : "v"(lo), "v"(hi));
  return r;
}

// K=16 bf16 MFMA (P stays in registers as the B operand)
__device__ __forceinline__ f32x4 mfma16(s16x4 a, s16x4 b, f32x4 c) {
#if __has_builtin(__builtin_amdgcn_mfma_f32_16x16x16_bf16)
  return __builtin_amdgcn_mfma_f32_16x16x16_bf16(a, b, c, 0, 0, 0);
#elif __has_builtin(__builtin_amdgcn_mfma_f32_16x16x16bf16_1k)
  return __builtin_amdgcn_mfma_f32_16x16x16bf16_1k(a, b, c, 0, 0, 0);
#else
  f32x4 d;
  asm("v_mfma_f32_16x16x16_bf16 %0, %1, %2, %3" : "=v"(d) : "v"(a), "v"(b), "v"(c));
  return d;
#endif
}

// ---------------- fp32 -> bf16 convert (x4 vectorized) ----------------
__global__ void cvt_bf16(const float* __restrict__ in, short* __restrict__ out, int n4) {
  int i = blockIdx.x * blockDim.x + threadIdx.x;
  if (i >= n4) return;
  f32x4 v = reinterpret_cast<const f32x4*>(in)[i];
  s16x4 o;
  o.x = f2bf(v.x); o.y = f2bf(v.y); o.z = f2bf(v.z); o.w = f2bf(v.w);
  reinterpret_cast<s16x4*>(out)[i] = o;
}

// ---------------- 128x128 bf16 GEMM, C = A * Bt^T (both K-contiguous) ----------------
// MODE 0: QKV epilogue -> scatter to q [B,H,T,64] (scaled log2e/8), k [B,H,T,64],
//         and V TRANSPOSED vt [B,H,64,T] (packed b64 stores along t)
// MODE 1: plain fp32 store to Cout [M,N]
#define BK 32

template<int MODE>
__global__ __launch_bounds__(256) void gemm_bt(
    const short* __restrict__ A, const short* __restrict__ Bt, int K, int N,
    float* __restrict__ Cout,
    short* __restrict__ qb, short* __restrict__ kb, short* __restrict__ vtb)
{
  __shared__ __align__(16) short As[128*BK];
  __shared__ __align__(16) short Bs[128*BK];
  const int tid = threadIdx.x;
  const int lane = tid & 63, wid = tid >> 6;
  const int wr = wid >> 1, wc = wid & 1;
  const int bm = blockIdx.y, bn = blockIdx.x;
  const int r16 = lane & 15, g = lane >> 4;

  f32x4 acc[4][4];
#pragma unroll
  for (int i = 0; i < 4; ++i)
#pragma unroll
    for (int j = 0; j < 4; ++j) acc[i][j] = (f32x4)0.0f;

  const int srow = lane >> 2;
  const int scol = (lane & 3) * 8;
  const int ch0 = wid * 2;

  const int nk = K / BK;
  for (int kt = 0; kt < nk; ++kt) {
    const int k0 = kt * BK;
#pragma unroll
    for (int c = 0; c < 2; ++c) {
      const int chunk = ch0 + c;
      const int row = chunk * 16 + srow;
      const short* ga = A  + (size_t)(bm*128 + row)*K + k0 + scol;
      const short* gb = Bt + (size_t)(bn*128 + row)*K + k0 + scol;
      __builtin_amdgcn_global_load_lds((const __attribute__((address_space(1))) void*)ga,
                                       (__attribute__((address_space(3))) void*)(&As[chunk*512]), 16, 0, 0);
      __builtin_amdgcn_global_load_lds((const __attribute__((address_space(1))) void*)gb,
                                       (__attribute__((address_space(3))) void*)(&Bs[chunk*512]), 16, 0, 0);
    }
    __syncthreads();

    bf16x8 af[4], bfv[4];
#pragma unroll
    for (int mi = 0; mi < 4; ++mi)
      af[mi] = *reinterpret_cast<const bf16x8*>(&As[(wr*64 + mi*16 + r16)*BK + g*8]);
#pragma unroll
    for (int ni = 0; ni < 4; ++ni)
      bfv[ni] = *reinterpret_cast<const bf16x8*>(&Bs[(wc*64 + ni*16 + r16)*BK + g*8]);
#pragma unroll
    for (int mi = 0; mi < 4; ++mi)
#pragma unroll
      for (int ni = 0; ni < 4; ++ni)
        acc[mi][ni] = __builtin_amdgcn_mfma_f32_16x16x32_bf16(af[mi], bfv[ni], acc[mi][ni], 0, 0, 0);
    __syncthreads();
  }

  // epilogue: D layout col = lane&15, row = (lane>>4)*4 + r
#pragma unroll
  for (int mi = 0; mi < 4; ++mi) {
    const int row0 = bm*128 + wr*64 + mi*16 + g*4;
#pragma unroll
    for (int ni = 0; ni < 4; ++ni) {
      const int col_g = bn*128 + wc*64 + ni*16 + r16;
      if (MODE == 1) {
#pragma unroll
        for (int r = 0; r < 4; ++r)
          Cout[(size_t)(row0 + r) * N + col_g] = acc[mi][ni][r];
      } else {
        const int which = col_g >> 10;          // 0=q 1=k 2=v
        const int hd = col_g & 1023;
        const int h = hd >> 6, d = hd & 63;
        const int b = row0 >> 11, t0 = row0 & 2047;
        const int bh = b*Hh + h;
        if (which == 0) {
#pragma unroll
          for (int r = 0; r < 4; ++r)
            qb[(((size_t)bh*Tt + t0 + r) << 6) + d] = f2bf(acc[mi][ni][r] * 0.18033688f); // log2e/8
        } else if (which == 1) {
#pragma unroll
          for (int r = 0; r < 4; ++r)
            kb[(((size_t)bh*Tt + t0 + r) << 6) + d] = f2bf(acc[mi][ni][r]);
        } else {
          // transposed V: t contiguous along register index -> one packed b64 store
          u32x2 w;
          w.x = cvtpk(acc[mi][ni][0], acc[mi][ni][1]);
          w.y = cvtpk(acc[mi][ni][2], acc[mi][ni][3]);
          *reinterpret_cast<u32x2*>(vtb + ((size_t)bh*DHd + d)*Tt + t0) = w;
        }
      }
    }
  }
}

// ---------------- flash attention, causal + key mask ----------------
// R7 structure (best measured: 111us): 1024 blocks, 4 waves, 32 q-rows/wave,
// XCD-clustered bh, heavy-first balanced qi permutation.
// NEW: K/V staged via global_load_lds with PRE-SWIZZLED global source
// (linear LDS dest + swizzled read = same involution; rule #21). Staging is
// fire-and-forget, drained by the end-of-tile barrier -> no kr/vr VGPRs,
// no ds_writes, no vmcnt stall in the wave stream.
__global__ __launch_bounds__(256) void attn_fwd(
    const short* __restrict__ qbf, const short* __restrict__ kbf,
    const short* __restrict__ vtb, const int* __restrict__ am,
    short* __restrict__ ob)
{
  __shared__ __align__(16) short Ks[2][64*64];
  __shared__ __align__(16) short Vts[2][64*64];
  const int tid = threadIdx.x;
  const int lane = tid & 63, wid = tid >> 6;
  const int r16 = lane & 15, g = lane >> 4;

  // XCD-clustered, heavy-first balanced mapping (R7)
  const int lin = blockIdx.x;            // 0..1023
  const int xcd = lin & 7;
  const int idx = lin >> 3;              // 0..127
  const int bh  = xcd * 8 + (idx & 7);
  const int qi_raw = idx >> 3;           // 0..15
  const int grp = qi_raw >> 2, rem = qi_raw & 3;
  const int qi = (grp == 0) ? 15 - rem : (grp == 1) ? rem : (grp == 2) ? 11 - rem : 4 + rem;
  const int b = bh >> 4, h = bh & 15;
  const int q0 = qi * 128;
  const int wq0 = q0 + wid * 32;

  const size_t kbase = (size_t)bh * Tt * DHd;
  const size_t vbase = (size_t)bh * DHd * Tt;

  // staging coords: thread -> (row, 16B-slot); LDS dest is linear in tid
  const int srow0 = tid >> 3;            // 0..31
  const int p8    = tid & 7;             // 16B slot
  const int ubase = tid & 448;           // wid*64 (wave-uniform dest base)

  // stage tile starting at key t0 into slot: pre-swizzled global source
#define ASTAGE(SLOT, T0) do {                                                  \
    _Pragma("unroll")                                                          \
    for (int c_ = 0; c_ < 2; ++c_) {                                           \
      const int row_ = c_*32 + srow0;                                          \
      const int sp_  = (p8 ^ (row_ & 7)) * 8;                                  \
      const short* gk_ = kbf + kbase + (size_t)((T0) + row_)*DHd + sp_;        \
      const short* gv_ = vtb + vbase + (size_t)row_*Tt + (T0) + sp_;           \
      __builtin_amdgcn_global_load_lds(                                        \
          (const __attribute__((address_space(1))) void*)gk_,                  \
          (__attribute__((address_space(3))) void*)(&Ks[SLOT][(c_*256 + ubase)*8]), 16, 0, 0); \
      __builtin_amdgcn_global_load_lds(                                        \
          (const __attribute__((address_space(1))) void*)gv_,                  \
          (__attribute__((address_space(3))) void*)(&Vts[SLOT][(c_*256 + ubase)*8]), 16, 0, 0); \
    }                                                                          \
  } while (0)

  // Q fragments (B-operand of swapped QK^T): q-col = r16, k = g*8+e
  bf16x8 qf[2][2];
#pragma unroll
  for (int m = 0; m < 2; ++m) {
    const short* qbase = qbf + ((size_t)bh*Tt + wq0 + m*16 + r16)*DHd;
    qf[m][0] = *reinterpret_cast<const bf16x8*>(qbase + g*8);
    qf[m][1] = *reinterpret_cast<const bf16x8*>(qbase + 32 + g*8);
  }

  f32x4 o[2][4];
  float mrow[2], lrow[2];
#pragma unroll
  for (int m = 0; m < 2; ++m) {
    mrow[m] = -INFINITY; lrow[m] = 0.f;
#pragma unroll
    for (int i = 0; i < 4; ++i) o[m][i] = (f32x4)0.0f;
  }

  const int nkv = 2*qi + 2;
  int amv = am[b*Tt + lane];

  // prologue: stage tile 0 (barrier drains vmcnt)
  ASTAGE(0, 0);
  __syncthreads();

  for (int kv = 0; kv < nkv; ++kv) {
    const int cur = kv & 1;
    const int kv0 = kv * 64;
    const unsigned long long mb = __ballot(amv != 0);
    int amv_next = 0;
    if (kv + 1 < nkv) {       // fire-and-forget next-tile staging + am prefetch
      ASTAGE(cur ^ 1, kv0 + 64);
      amv_next = am[b*Tt + kv0 + 64 + lane];
    }

    if (kv0 <= wq0 + 31) {    // skip fully-above-diagonal tiles (wave-uniform)
      const char* kbp = (const char*)Ks[cur];
      const char* vbp = (const char*)Vts[cur];
      const int swzr = (r16 & 7) << 4;

      // ---- S^T = K · Q^T (16x16x32) ----
      f32x4 st[2][4];
      __builtin_amdgcn_s_setprio(1);
#pragma unroll
      for (int kt = 0; kt < 4; ++kt) {
        const int rb = (kt*16 + r16)*128;
        const bf16x8 ka0 = *reinterpret_cast<const bf16x8*>(kbp + ((rb + g*16) ^ swzr));
        const bf16x8 ka1 = *reinterpret_cast<const bf16x8*>(kbp + ((rb + 64 + g*16) ^ swzr));
#pragma unroll
        for (int m = 0; m < 2; ++m) {
          f32x4 t = (f32x4)0.0f;
          t = __builtin_amdgcn_mfma_f32_16x16x32_bf16(ka0, qf[m][0], t, 0, 0, 0);
          t = __builtin_amdgcn_mfma_f32_16x16x32_bf16(ka1, qf[m][1], t, 0, 0, 0);
          st[m][kt] = t;
        }
      }
      __builtin_amdgcn_s_setprio(0);

      // ---- masking (wave-uniform branch; usually skipped) ----
      const bool notall = (mb != ~0ull);
      const bool diag = (kv0 + 63 > wq0);
      if (diag || notall) {
#pragma unroll
        for (int m = 0; m < 2; ++m) {
          const int qrow = wq0 + m*16 + r16;
#pragma unroll
          for (int kt = 0; kt < 4; ++kt)
#pragma unroll
            for (int r = 0; r < 4; ++r) {
              const int kl = kt*16 + g*4 + r;
              bool ok = !diag || (kv0 + kl <= qrow);
              if (notall) ok = ok && ((mb >> kl) & 1ull);
              if (!ok) st[m][kt][r] = -3.0e38f;
            }
        }
      }

      // ---- in-register online softmax + defer-rescale (THR=8, log2 dom) ----
      float mx[2];
#pragma unroll
      for (int m = 0; m < 2; ++m) {
        f32x4 t0, t1;
#pragma unroll
        for (int i = 0; i < 4; ++i) { t0[i] = fmaxf(st[m][0][i], st[m][1][i]); t1[i] = fmaxf(st[m][2][i], st[m][3][i]); }
#pragma unroll
        for (int i = 0; i < 4; ++i) t0[i] = fmaxf(t0[i], t1[i]);
        mx[m] = fmaxf(fmaxf(t0[0], t0[1]), fmaxf(t0[2], t0[3]));
      }
      {
        float a0 = __shfl_xor(mx[0], 16), a1 = __shfl_xor(mx[1], 16);
        mx[0] = fmaxf(mx[0], a0); mx[1] = fmaxf(mx[1], a1);
        a0 = __shfl_xor(mx[0], 32); a1 = __shfl_xor(mx[1], 32);
        mx[0] = fmaxf(mx[0], a0); mx[1] = fmaxf(mx[1], a1);
      }
      const bool need = __any((mx[0] > mrow[0] + 8.f) || (mx[1] > mrow[1] + 8.f));
      if (need) {
#pragma unroll
        for (int m = 0; m < 2; ++m) {
          const float mnew = fmaxf(mrow[m], mx[m]);
          const float alpha = __builtin_amdgcn_exp2f(mrow[m] - mnew);
          mrow[m] = mnew;
          lrow[m] *= alpha;
#pragma unroll
          for (int dt = 0; dt < 4; ++dt) o[m][dt] *= alpha;
        }
      }

      // exp + pack P into registers (B-frags of 16x16x16: k = g*4+e per kt)
      s16x4 pb[2][4];
      float rsum[2];
#pragma unroll
      for (int m = 0; m < 2; ++m) {
#pragma unroll
        for (int kt = 0; kt < 4; ++kt)
#pragma unroll
          for (int r = 0; r < 4; ++r)
            st[m][kt][r] = __builtin_amdgcn_exp2f(st[m][kt][r] - mrow[m]);
#pragma unroll
        for (int kt = 0; kt < 4; ++kt) {
          u32x2 w;
          w.x = cvtpk(st[m][kt][0], st[m][kt][1]);
          w.y = cvtpk(st[m][kt][2], st[m][kt][3]);
          pb[m][kt] = __builtin_bit_cast(s16x4, w);
        }
        f32x4 s4;
#pragma unroll
        for (int i = 0; i < 4; ++i) s4[i] = st[m][0][i] + st[m][1][i] + st[m][2][i] + st[m][3][i];
        rsum[m] = (s4[0] + s4[1]) + (s4[2] + s4[3]);
      }
      {
        float a0 = __shfl_xor(rsum[0], 16), a1 = __shfl_xor(rsum[1], 16);
        rsum[0] += a0; rsum[1] += a1;
        a0 = __shfl_xor(rsum[0], 32); a1 = __shfl_xor(rsum[1], 32);
        rsum[0] += a0; rsum[1] += a1;
      }
      lrow[0] += rsum[0]; lrow[1] += rsum[1];

      // ---- O^T += Vt · P^T : 16x16x16 MFMA, P direct from registers ----
      __builtin_amdgcn_s_setprio(1);
#pragma unroll
      for (int dt = 0; dt < 4; ++dt) {
        const int row = dt*16 + r16;
        const int rb = row*128;
        const int r7 = row & 7;
#pragma unroll
        for (int kt = 0; kt < 4; ++kt) {
          const s16x4 va = *reinterpret_cast<const s16x4*>(
              vbp + rb + ((((kt<<1) + (g>>1)) ^ r7) << 4) + (g & 1)*8);
          o[0][dt] = mfma16(va, pb[0][kt], o[0][dt]);
          o[1][dt] = mfma16(va, pb[1][kt], o[1][dt]);
        }
      }
      __builtin_amdgcn_s_setprio(0);
    }

    amv = amv_next;
    // single barrier: buf[cur] reads done; staged writes to buf[cur^1] landed
    __syncthreads();
  }

  // ---- normalize + store O (lane holds q=r16, d=dt*16+g*4+r contiguous) ----
#pragma unroll
  for (int m = 0; m < 2; ++m) {
    const float inv = (mrow[m] > -1e37f) ? 1.0f / lrow[m] : 0.f;
    short* obase = ob + ((size_t)(b*Tt + wq0 + m*16 + r16))*Cc + h*DHd;
#pragma unroll
    for (int dt = 0; dt < 4; ++dt) {
      u32x2 w;
      w.x = cvtpk(o[m][dt][0]*inv, o[m][dt][1]*inv);
      w.y = cvtpk(o[m][dt][2]*inv, o[m][dt][3]*inv);
      *reinterpret_cast<u32x2*>(obase + dt*16 + g*4) = w;
    }
  }
#undef ASTAGE
}

// ---------------- launcher ----------------
extern "C" void kernel_launch(void* const* d_in, const int* in_sizes, int n_in,
                              void* d_out, int out_size, void* d_ws, size_t ws_size,
                              hipStream_t stream) {
  const float* x    = (const float*)d_in[0];
  const int*   am   = (const int*)d_in[1];
  const float* wqkv = (const float*)d_in[2];
  const float* wout = (const float*)d_in[3];
  float* out = (float*)d_out;

  const size_t mc = (size_t)Mm * Cc;        // 8,388,608
  short* ws    = (short*)d_ws;
  short* xb    = ws;                        // [8192,1024] bf16
  short* wqkvb = xb + mc;                   // [3072,1024]
  short* woutb = wqkvb + (size_t)3*Cc*Cc;   // [1024,1024]
  short* qbuf  = woutb + (size_t)Cc*Cc;     // [B,H,T,64] (pre-scaled by log2e/8)
  short* kbuf  = qbuf + mc;                 // [B,H,T,64]
  short* vtbuf = kbuf + mc;                 // [B,H,64,T] (transposed V)
  short* attnb = xb;                        // reuse x buffer after QKV GEMM

  cvt_bf16<<<(int)((mc/4 + 255)/256), 256, 0, stream>>>(x, xb, (int)(mc/4));
  cvt_bf16<<<(3*Cc*Cc/4 + 255)/256, 256, 0, stream>>>(wqkv, wqkvb, 3*Cc*Cc/4);
  cvt_bf16<<<(Cc*Cc/4 + 255)/256, 256, 0, stream>>>(wout, woutb, Cc*Cc/4);

  gemm_bt<0><<<dim3(3*Cc/128, Mm/128), 256, 0, stream>>>(
      xb, wqkvb, Cc, 3*Cc, nullptr, qbuf, kbuf, vtbuf);

  attn_fwd<<<dim3(Bb*Hh*Tt/128), 256, 0, stream>>>(qbuf, kbuf, vtbuf, am, attnb);

  gemm_bt<1><<<dim3(Cc/128, Mm/128), 256, 0, stream>>>(
      attnb, woutb, Cc, Cc, out, nullptr, nullptr, nullptr);
}